// Round 4
// baseline (7895.219 us; speedup 1.0000x reference)
//
#include <hip/hip_runtime.h>

#define NIN  100
#define NOUT 100
#define NHID 500
#define BATCH 256
#define TLEN 300

// ws layout (float offsets)
#define WS_WCT 0        // [100][500]  W_cT[i][j] = (W_ih@W_in)[j][i]
#define WS_BC  50000    // [500]       b_c = W_ih@b_in + b_ih
#define WS_WOT 50500    // [500][100]  W_outT[k][o] = W_out[o][k]
#define WS_HB0 100500   // [256][500]  h double-buffer 0
#define WS_HB1 228500   // [256][500]  h double-buffer 1
#define WS_CNT 356500   // int[32*300] barrier counters

// ---------------- prep: fused weights, transposes, h0 copy, counter zeroing ----------------
__global__ __launch_bounds__(256) void prep_kernel(
    const float* __restrict__ W_in, const float* __restrict__ b_in,
    const float* __restrict__ W_ih, const float* __restrict__ b_ih,
    const float* __restrict__ W_out, const float* __restrict__ hidden0,
    float* __restrict__ ws)
{
  int id = blockIdx.x * 256 + threadIdx.x;
  if (id < 50000) {
    int j = id / NIN, i = id % NIN;            // W_c[j][i] = sum_m W_ih[j][m]*W_in[m][i]
    float s = 0.f;
    #pragma unroll 4
    for (int m = 0; m < NHID; m++) s = fmaf(W_ih[j*NHID + m], W_in[m*NIN + i], s);
    ws[WS_WCT + i*NHID + j] = s;               // store transposed: W_cT[i][j]
  } else if (id < 50500) {
    int j = id - 50000;
    float s = b_ih[j];
    #pragma unroll 4
    for (int m = 0; m < NHID; m++) s = fmaf(W_ih[j*NHID + m], b_in[m], s);
    ws[WS_BC + j] = s;
  } else if (id < 100500) {
    int v = id - 50500;                        // v = k*100 + o
    int k = v / NOUT, o = v % NOUT;
    ws[WS_WOT + v] = W_out[o*NHID + k];
  } else if (id < 228500) {
    ws[WS_HB0 + (id - 100500)] = hidden0[id - 100500];
  } else if (id < 238100) {
    ((int*)(ws + WS_CNT))[id - 228500] = 0;
  }
}

// ---------------- pre = input @ W_cT + b_c  ->  written into d_out hidden region ----------------
__global__ __launch_bounds__(256) void pre_gemm_kernel(
    const float* __restrict__ in, const float* __restrict__ ws, float* __restrict__ hid)
{
  __shared__ float A_s[100][68];   // [k][row] transposed input tile
  __shared__ float W_s[100][68];   // [k][j]   W_cT tile
  const int r0 = blockIdx.x * 64;
  const int j0 = blockIdx.y * 64;
  const int tid = threadIdx.x;

  for (int idx = tid; idx < 64*25; idx += 256) {
    int r = idx / 25, kq = idx % 25;
    float4 v = ((const float4*)(in + (size_t)(r0 + r)*NIN))[kq];
    A_s[4*kq+0][r] = v.x; A_s[4*kq+1][r] = v.y; A_s[4*kq+2][r] = v.z; A_s[4*kq+3][r] = v.w;
  }
  for (int idx = tid; idx < 100*16; idx += 256) {
    int k = idx / 16, c4 = idx % 16;
    int j = j0 + c4*4;
    float4 v = make_float4(0.f,0.f,0.f,0.f);
    if (j + 3 < NHID) v = *(const float4*)(ws + WS_WCT + (size_t)k*NHID + j);
    else {
      if (j+0 < NHID) v.x = ws[WS_WCT + k*NHID + j+0];
      if (j+1 < NHID) v.y = ws[WS_WCT + k*NHID + j+1];
      if (j+2 < NHID) v.z = ws[WS_WCT + k*NHID + j+2];
    }
    *(float4*)&W_s[k][c4*4] = v;
  }
  __syncthreads();

  const int jj = tid & 15, rr = tid >> 4;
  float acc[4][4] = {};
  #pragma unroll 4
  for (int k = 0; k < 100; k++) {
    float4 av = *(const float4*)&A_s[k][rr*4];
    float4 wv = *(const float4*)&W_s[k][jj*4];
    float aa[4] = {av.x, av.y, av.z, av.w};
    float ww[4] = {wv.x, wv.y, wv.z, wv.w};
    #pragma unroll
    for (int r = 0; r < 4; r++)
      #pragma unroll
      for (int c = 0; c < 4; c++)
        acc[r][c] = fmaf(aa[r], ww[c], acc[r][c]);
  }
  #pragma unroll
  for (int r = 0; r < 4; r++) {
    int row = r0 + rr*4 + r;
    #pragma unroll
    for (int c = 0; c < 4; c++) {
      int j = j0 + jj*4 + c;
      if (j < NHID) hid[(size_t)row*NHID + j] = acc[r][c] + ws[WS_BC + j];
    }
  }
}

// ---------------- persistent recurrence: W_hh in VGPRs, h broadcast from LDS ----------------
// grid 256 = 32 batch-groups (8 rows) x 8 j-tiles (64 cols). Regular launch; LDS 55.6KB +
// launch_bounds(256,2) -> capacity 2 blocks/CU, grid only 1/CU -> residency robust.
// thread (ks = tid>>4, jg = tid&15): owns 4 j-cols, K-slice [ks*32, ks*32+32),
// computes partials for all 8 rows; cross-ks reduction through padded LDS.
__global__ __launch_bounds__(256, 2) void rnn_step_kernel(
    const float* __restrict__ W_hh, const float* __restrict__ b_hh,
    const float* __restrict__ alpha_w, float* __restrict__ ws,
    float* __restrict__ hid, float* __restrict__ hfinal)
{
  __shared__ float h_s[8*576];          // [r][ks*36 + kk]  swizzled slices (18,432 B)
  __shared__ float red[16*580];         // [ks][jg*36 + c]  c = jj*8 + r   (37,120 B)

  const int tid = threadIdx.x;
  const int bt  = blockIdx.x >> 3;      // batch group 0..31
  const int jt  = blockIdx.x & 7;       // j tile 0..7
  const int r0  = bt * 8;
  const int j0  = jt * 64;
  const int ks  = tid >> 4;             // 0..15
  const int jg  = tid & 15;             // 0..15

  float* hb0 = ws + WS_HB0;
  float* hb1 = ws + WS_HB1;
  int* cnt = (int*)(ws + WS_CNT) + bt * TLEN;

  // ---- W slice into registers (persists across all 300 steps) ----
  float4 Wr[4][8];
  #pragma unroll
  for (int jj = 0; jj < 4; jj++) {
    int j = j0 + jg*4 + jj;
    #pragma unroll
    for (int kq = 0; kq < 8; kq++) {
      int k = ks*32 + kq*4;
      float4 v = make_float4(0.f,0.f,0.f,0.f);
      if (j < NHID && k + 3 < NHID) v = *(const float4*)(W_hh + (size_t)j*NHID + k);
      Wr[jj][kq] = v;
    }
  }

  // ---- epilogue constants: this thread finalizes outputs o = 2*tid, 2*tid+1 ----
  const int oA  = tid * 2;
  const int jlE = oA >> 3;              // 0..63
  const int rE  = oA & 7;               // even row
  const int jE  = j0 + jlE;
  const bool jvE = (jE < NHID);
  const float aE  = jvE ? alpha_w[jE] : 0.f;
  const float bhE = jvE ? b_hh[jE]    : 0.f;
  const int jgE = jlE >> 2;
  const int cE  = (jlE & 3)*8 + rE;     // red c-index
  const int hIdxE = (jE >> 5)*36 + (jE & 31);   // h_old LDS offset for col jE

  for (int t = 0; t < TLEN; t++) {
    const float* hcur = (t & 1) ? hb1 : hb0;
    float*       hnxt = (t & 1) ? hb0 : hb1;

    // prefetch pre-activation values (this thread's exclusive (b,t,j) slots)
    size_t offA = ((size_t)(r0 + rE)*TLEN + t)*NHID + jE;
    size_t offB = ((size_t)(r0 + rE + 1)*TLEN + t)*NHID + jE;
    float preA = jvE ? hid[offA] : 0.f;
    float preB = jvE ? hid[offB] : 0.f;

    // stage h[8 rows][500] into swizzled LDS (1000 float4)
    #pragma unroll
    for (int i = 0; i < 4; i++) {
      int f = tid + 256*i;
      if (f < 1000) {
        int r = f / 125, kq = f % 125;          // k = 4*kq
        float4 v = *(const float4*)(hcur + (size_t)(r0 + r)*NHID + kq*4);
        int kss = kq >> 3, kk = (kq*4) & 31;
        *(float4*)&h_s[r*576 + kss*36 + kk] = v;
      }
    }
    if (tid < 96) {                             // zero tail of slice 15 (k >= 500)
      int r = tid / 12, kk = 20 + (tid % 12);
      h_s[r*576 + 15*36 + kk] = 0.f;
    }
    __syncthreads();

    // ---- partial dot-products: 8 rows x 4 j over this thread's 32-wide K slice ----
    float acc[8][4];
    #pragma unroll
    for (int r = 0; r < 8; r++)
      #pragma unroll
      for (int jj = 0; jj < 4; jj++) acc[r][jj] = 0.f;

    const float* hb = &h_s[ks*36];
    #pragma unroll
    for (int kq = 0; kq < 8; kq++) {
      #pragma unroll
      for (int r = 0; r < 8; r++) {
        float4 hv = *(const float4*)&hb[r*576 + kq*4];   // multicast, conflict-free
        #pragma unroll
        for (int jj = 0; jj < 4; jj++) {
          acc[r][jj] = fmaf(Wr[jj][kq].x, hv.x, acc[r][jj]);
          acc[r][jj] = fmaf(Wr[jj][kq].y, hv.y, acc[r][jj]);
          acc[r][jj] = fmaf(Wr[jj][kq].z, hv.z, acc[r][jj]);
          acc[r][jj] = fmaf(Wr[jj][kq].w, hv.w, acc[r][jj]);
        }
      }
    }

    // ---- write partials: red[ks][jg][jj*8 + r] ----
    float* rw = &red[ks*580 + jg*36];
    #pragma unroll
    for (int jj = 0; jj < 4; jj++)
      #pragma unroll
      for (int rq = 0; rq < 2; rq++) {
        float4 v = make_float4(acc[rq*4+0][jj], acc[rq*4+1][jj],
                               acc[rq*4+2][jj], acc[rq*4+3][jj]);
        *(float4*)&rw[jj*8 + rq*4] = v;
      }
    __syncthreads();

    // ---- reduce over 16 K-slices + epilogue for outputs (rE,jE) and (rE+1,jE) ----
    float sA = 0.f, sB = 0.f;
    const float* rr_ = &red[jgE*36 + cE];
    #pragma unroll
    for (int k2 = 0; k2 < 16; k2++) {
      sA += rr_[k2*580];
      sB += rr_[k2*580 + 1];
    }
    float holdA = h_s[rE*576 + hIdxE];
    float holdB = h_s[(rE+1)*576 + hIdxE];
    float hcA = fmaxf(sA + bhE + preA, 0.f);
    float hcB = fmaxf(sB + bhE + preB, 0.f);
    float hnA = (1.f - aE)*holdA + aE*hcA;
    float hnB = (1.f - aE)*holdB + aE*hcB;
    if (jvE) {
      hnxt[(size_t)(r0 + rE)*NHID + jE]     = hnA;
      hnxt[(size_t)(r0 + rE + 1)*NHID + jE] = hnB;
      hid[offA] = hnA;
      hid[offB] = hnB;
      if (t == TLEN-1) {
        hfinal[(size_t)(r0 + rE)*NHID + jE]     = hnA;
        hfinal[(size_t)(r0 + rE + 1)*NHID + jE] = hnB;
      }
    }
    __syncthreads();   // intra-block: all threads' stores drained (vmcnt0 before s_barrier)

    // group barrier: release add (wbl2) / acquire spin (inv) handles cross-XCD L2
    if (tid == 0) {
      __hip_atomic_fetch_add(&cnt[t], 1, __ATOMIC_RELEASE, __HIP_MEMORY_SCOPE_AGENT);
      int guard = 0;
      while (__hip_atomic_load(&cnt[t], __ATOMIC_ACQUIRE, __HIP_MEMORY_SCOPE_AGENT) < 8) {
        if (++guard > (1 << 21)) break;   // bail-out: wrong answer, never a hang
        __builtin_amdgcn_s_sleep(1);
      }
    }
    __syncthreads();
  }
}

// ---------------- output projection: out = hidden_list @ W_outT + b_out ----------------
__global__ __launch_bounds__(256) void out_proj_kernel(
    const float* __restrict__ hid, const float* __restrict__ ws,
    const float* __restrict__ b_out, float* __restrict__ outp)
{
  __shared__ float A_s[100][68];
  __shared__ float W_s[100][68];
  const int r0 = blockIdx.x * 64;
  const int o0 = blockIdx.y * 64;
  const int tid = threadIdx.x;
  const int jj = tid & 15, rr = tid >> 4;
  float acc[4][4] = {};

  for (int kc = 0; kc < NHID; kc += 100) {
    __syncthreads();
    for (int idx = tid; idx < 64*25; idx += 256) {
      int r = idx / 25, kq = idx % 25;
      float4 v = ((const float4*)(hid + (size_t)(r0 + r)*NHID + kc))[kq];
      A_s[4*kq+0][r] = v.x; A_s[4*kq+1][r] = v.y; A_s[4*kq+2][r] = v.z; A_s[4*kq+3][r] = v.w;
    }
    for (int idx = tid; idx < 100*16; idx += 256) {
      int k = idx / 16, c4 = idx % 16;
      int o = o0 + c4*4;
      float4 v = make_float4(0.f,0.f,0.f,0.f);
      if (o + 3 < NOUT) v = *(const float4*)(ws + WS_WOT + (size_t)(kc + k)*NOUT + o);
      *(float4*)&W_s[k][c4*4] = v;
    }
    __syncthreads();
    #pragma unroll 2
    for (int k = 0; k < 100; k++) {
      float4 av = *(const float4*)&A_s[k][rr*4];
      float4 wv = *(const float4*)&W_s[k][jj*4];
      float aa[4] = {av.x, av.y, av.z, av.w};
      float ww[4] = {wv.x, wv.y, wv.z, wv.w};
      #pragma unroll
      for (int r = 0; r < 4; r++)
        #pragma unroll
        for (int c = 0; c < 4; c++)
          acc[r][c] = fmaf(aa[r], ww[c], acc[r][c]);
    }
  }
  #pragma unroll
  for (int r = 0; r < 4; r++) {
    int row = r0 + rr*4 + r;
    #pragma unroll
    for (int c = 0; c < 4; c++) {
      int o = o0 + jj*4 + c;
      if (o < NOUT) outp[(size_t)row*NOUT + o] = acc[r][c] + b_out[o];
    }
  }
}

extern "C" void kernel_launch(void* const* d_in, const int* in_sizes, int n_in,
                              void* d_out, int out_size, void* d_ws, size_t ws_size,
                              hipStream_t stream)
{
  const float* input   = (const float*)d_in[0];
  const float* hidden0 = (const float*)d_in[1];
  const float* W_in    = (const float*)d_in[2];
  const float* b_in    = (const float*)d_in[3];
  const float* W_ih    = (const float*)d_in[4];
  const float* b_ih    = (const float*)d_in[5];
  const float* W_hh    = (const float*)d_in[6];
  const float* b_hh    = (const float*)d_in[7];
  const float* W_out   = (const float*)d_in[8];
  const float* b_out   = (const float*)d_in[9];
  const float* alpha_w = (const float*)d_in[10];

  float* ws   = (float*)d_ws;
  float* hid  = (float*)d_out;                        // [256][300][500]
  float* outp = hid  + (size_t)BATCH*TLEN*NHID;       // [256][300][100]
  float* hfin = outp + (size_t)BATCH*TLEN*NOUT;       // [256][500]

  hipLaunchKernelGGL(prep_kernel,     dim3(931),      dim3(256), 0, stream,
                     W_in, b_in, W_ih, b_ih, W_out, hidden0, ws);
  hipLaunchKernelGGL(pre_gemm_kernel, dim3(1200, 8),  dim3(256), 0, stream,
                     input, ws, hid);
  hipLaunchKernelGGL(rnn_step_kernel, dim3(256),      dim3(256), 0, stream,
                     W_hh, b_hh, alpha_w, ws, hid, hfin);
  hipLaunchKernelGGL(out_proj_kernel, dim3(1200, 2),  dim3(256), 0, stream,
                     hid, ws, b_out, outp);
}

// Round 6
// 5290.392 us; speedup vs baseline: 1.4924x; 1.4924x over previous
//
#include <hip/hip_runtime.h>

#define NIN  100
#define NOUT 100
#define NHID 500
#define BATCH 256
#define TLEN 300

// ws layout (float offsets)
#define WS_WCT 0        // [100][500]  W_cT[i][j] = (W_ih@W_in)[j][i]
#define WS_BC  50000    // [500]       b_c = W_ih@b_in + b_ih
#define WS_WOT 50500    // [500][100]  W_outT[k][o] = W_out[o][k]
#define WS_HB0 100500   // [256][500]  h double-buffer 0
#define WS_HB1 228500   // [256][500]  h double-buffer 1
#define WS_CNT 356500   // int[32*300] barrier counters

// relaxed agent-scope ops: cache-BYPASSING (sc0/sc1), no wbl2/buffer_inv emitted
__device__ __forceinline__ void store_xcd(float* p, float v) {
  __hip_atomic_store((int*)p, __float_as_int(v), __ATOMIC_RELAXED, __HIP_MEMORY_SCOPE_AGENT);
}
__device__ __forceinline__ unsigned long long load_xcd_u64(const void* p) {
  return __hip_atomic_load((const unsigned long long*)p, __ATOMIC_RELAXED, __HIP_MEMORY_SCOPE_AGENT);
}

// ---------------- prep: fused weights, transposes, h0 copy, counter zeroing ----------------
__global__ __launch_bounds__(256) void prep_kernel(
    const float* __restrict__ W_in, const float* __restrict__ b_in,
    const float* __restrict__ W_ih, const float* __restrict__ b_ih,
    const float* __restrict__ W_out, const float* __restrict__ hidden0,
    float* __restrict__ ws)
{
  int id = blockIdx.x * 256 + threadIdx.x;
  if (id < 50000) {
    int j = id / NIN, i = id % NIN;            // W_c[j][i] = sum_m W_ih[j][m]*W_in[m][i]
    float s = 0.f;
    #pragma unroll 4
    for (int m = 0; m < NHID; m++) s = fmaf(W_ih[j*NHID + m], W_in[m*NIN + i], s);
    ws[WS_WCT + i*NHID + j] = s;               // store transposed: W_cT[i][j]
  } else if (id < 50500) {
    int j = id - 50000;
    float s = b_ih[j];
    #pragma unroll 4
    for (int m = 0; m < NHID; m++) s = fmaf(W_ih[j*NHID + m], b_in[m], s);
    ws[WS_BC + j] = s;
  } else if (id < 100500) {
    int v = id - 50500;                        // v = k*100 + o
    int k = v / NOUT, o = v % NOUT;
    ws[WS_WOT + v] = W_out[o*NHID + k];
  } else if (id < 228500) {
    ws[WS_HB0 + (id - 100500)] = hidden0[id - 100500];
  } else if (id < 238100) {
    ((int*)(ws + WS_CNT))[id - 228500] = 0;
  }
}

// ---------------- pre = input @ W_cT + b_c  ->  written into d_out hidden region ----------------
__global__ __launch_bounds__(256) void pre_gemm_kernel(
    const float* __restrict__ in, const float* __restrict__ ws, float* __restrict__ hid)
{
  __shared__ float A_s[100][68];   // [k][row] transposed input tile
  __shared__ float W_s[100][68];   // [k][j]   W_cT tile
  const int r0 = blockIdx.x * 64;
  const int j0 = blockIdx.y * 64;
  const int tid = threadIdx.x;

  for (int idx = tid; idx < 64*25; idx += 256) {
    int r = idx / 25, kq = idx % 25;
    float4 v = ((const float4*)(in + (size_t)(r0 + r)*NIN))[kq];
    A_s[4*kq+0][r] = v.x; A_s[4*kq+1][r] = v.y; A_s[4*kq+2][r] = v.z; A_s[4*kq+3][r] = v.w;
  }
  for (int idx = tid; idx < 100*16; idx += 256) {
    int k = idx / 16, c4 = idx % 16;
    int j = j0 + c4*4;
    float4 v = make_float4(0.f,0.f,0.f,0.f);
    if (j + 3 < NHID) v = *(const float4*)(ws + WS_WCT + (size_t)k*NHID + j);
    else {
      if (j+0 < NHID) v.x = ws[WS_WCT + k*NHID + j+0];
      if (j+1 < NHID) v.y = ws[WS_WCT + k*NHID + j+1];
      if (j+2 < NHID) v.z = ws[WS_WCT + k*NHID + j+2];
    }
    *(float4*)&W_s[k][c4*4] = v;
  }
  __syncthreads();

  const int jj = tid & 15, rr = tid >> 4;
  float acc[4][4] = {};
  #pragma unroll 4
  for (int k = 0; k < 100; k++) {
    float4 av = *(const float4*)&A_s[k][rr*4];
    float4 wv = *(const float4*)&W_s[k][jj*4];
    float aa[4] = {av.x, av.y, av.z, av.w};
    float ww[4] = {wv.x, wv.y, wv.z, wv.w};
    #pragma unroll
    for (int r = 0; r < 4; r++)
      #pragma unroll
      for (int c = 0; c < 4; c++)
        acc[r][c] = fmaf(aa[r], ww[c], acc[r][c]);
  }
  #pragma unroll
  for (int r = 0; r < 4; r++) {
    int row = r0 + rr*4 + r;
    #pragma unroll
    for (int c = 0; c < 4; c++) {
      int j = j0 + jj*4 + c;
      if (j < NHID) hid[(size_t)row*NHID + j] = acc[r][c] + ws[WS_BC + j];
    }
  }
}

// ---------------- persistent recurrence: W_hh in VGPRs, h broadcast from LDS ----------------
// grid 256 = 32 batch-groups (8 rows) x 8 j-tiles (64 cols). Cross-block exchange (hnxt, cnt)
// goes through RELAXED agent-scope atomics (cache-bypass, NO wbl2/inv). hid/hfinal streams
// stay normal stores (read only by later kernels; kernel-boundary flush covers them).
__global__ __launch_bounds__(256, 2) void rnn_step_kernel(
    const float* __restrict__ W_hh, const float* __restrict__ b_hh,
    const float* __restrict__ alpha_w, float* __restrict__ ws,
    float* __restrict__ hid, float* __restrict__ hfinal)
{
  __shared__ float h_s[8*576];          // [r][ks*36 + kk]  swizzled slices (18,432 B)
  __shared__ float red[16*580];         // [ks][jg*36 + c]  c = jj*8 + r   (37,120 B)

  const int tid = threadIdx.x;
  const int bt  = blockIdx.x >> 3;      // batch group 0..31
  const int jt  = blockIdx.x & 7;       // j tile 0..7
  const int r0  = bt * 8;
  const int j0  = jt * 64;
  const int ks  = tid >> 4;             // 0..15
  const int jg  = tid & 15;             // 0..15

  float* hb0 = ws + WS_HB0;
  float* hb1 = ws + WS_HB1;
  int* cnt = (int*)(ws + WS_CNT) + bt * TLEN;

  // ---- W slice into registers (persists across all 300 steps) ----
  float4 Wr[4][8];
  #pragma unroll
  for (int jj = 0; jj < 4; jj++) {
    int j = j0 + jg*4 + jj;
    #pragma unroll
    for (int kq = 0; kq < 8; kq++) {
      int k = ks*32 + kq*4;
      float4 v = make_float4(0.f,0.f,0.f,0.f);
      if (j < NHID && k + 3 < NHID) v = *(const float4*)(W_hh + (size_t)j*NHID + k);
      Wr[jj][kq] = v;
    }
  }

  // ---- epilogue constants: this thread finalizes outputs o = 2*tid, 2*tid+1 ----
  const int oA  = tid * 2;
  const int jlE = oA >> 3;              // 0..63
  const int rE  = oA & 7;               // even row
  const int jE  = j0 + jlE;
  const bool jvE = (jE < NHID);
  const float aE  = jvE ? alpha_w[jE] : 0.f;
  const float bhE = jvE ? b_hh[jE]    : 0.f;
  const int jgE = jlE >> 2;
  const int cE  = (jlE & 3)*8 + rE;     // red c-index
  const int hIdxE = (jE >> 5)*36 + (jE & 31);   // h_old LDS offset for col jE

  for (int t = 0; t < TLEN; t++) {
    const float* hcur = (t & 1) ? hb1 : hb0;
    float*       hnxt = (t & 1) ? hb0 : hb1;

    // prefetch pre-activation values (this thread's exclusive (b,t,j) slots; normal loads:
    // location only ever written by pre_gemm (prior kernel) and this thread at this t)
    size_t offA = ((size_t)(r0 + rE)*TLEN + t)*NHID + jE;
    size_t offB = ((size_t)(r0 + rE + 1)*TLEN + t)*NHID + jE;
    float preA = jvE ? hid[offA] : 0.f;
    float preB = jvE ? hid[offB] : 0.f;

    // stage h[8 rows][500] into swizzled LDS — cache-bypass 8B loads (other XCDs wrote it)
    #pragma unroll
    for (int i = 0; i < 4; i++) {
      int f = tid + 256*i;
      if (f < 1000) {
        int r = f / 125, kq = f % 125;          // k = 4*kq
        const float* src = hcur + (size_t)(r0 + r)*NHID + kq*4;   // 8B-aligned
        unsigned long long lo = load_xcd_u64(src);
        unsigned long long hi = load_xcd_u64(src + 2);
        int kss = kq >> 3, kk = (kq*4) & 31;
        float* dst = &h_s[r*576 + kss*36 + kk];                   // 16B-aligned
        ((unsigned long long*)dst)[0] = lo;
        ((unsigned long long*)dst)[1] = hi;
      }
    }
    if (tid < 96) {                             // zero tail of slice 15 (k >= 500)
      int r = tid / 12, kk = 20 + (tid % 12);
      h_s[r*576 + 15*36 + kk] = 0.f;
    }
    __syncthreads();

    // ---- partial dot-products: 8 rows x 4 j over this thread's 32-wide K slice ----
    float acc[8][4];
    #pragma unroll
    for (int r = 0; r < 8; r++)
      #pragma unroll
      for (int jj = 0; jj < 4; jj++) acc[r][jj] = 0.f;

    const float* hb = &h_s[ks*36];
    #pragma unroll
    for (int kq = 0; kq < 8; kq++) {
      #pragma unroll
      for (int r = 0; r < 8; r++) {
        float4 hv = *(const float4*)&hb[r*576 + kq*4];   // multicast, conflict-free
        #pragma unroll
        for (int jj = 0; jj < 4; jj++) {
          acc[r][jj] = fmaf(Wr[jj][kq].x, hv.x, acc[r][jj]);
          acc[r][jj] = fmaf(Wr[jj][kq].y, hv.y, acc[r][jj]);
          acc[r][jj] = fmaf(Wr[jj][kq].z, hv.z, acc[r][jj]);
          acc[r][jj] = fmaf(Wr[jj][kq].w, hv.w, acc[r][jj]);
        }
      }
    }

    // ---- write partials: red[ks][jg][jj*8 + r] ----
    float* rw = &red[ks*580 + jg*36];
    #pragma unroll
    for (int jj = 0; jj < 4; jj++)
      #pragma unroll
      for (int rq = 0; rq < 2; rq++) {
        float4 v = make_float4(acc[rq*4+0][jj], acc[rq*4+1][jj],
                               acc[rq*4+2][jj], acc[rq*4+3][jj]);
        *(float4*)&rw[jj*8 + rq*4] = v;
      }
    __syncthreads();

    // ---- reduce over 16 K-slices + epilogue for outputs (rE,jE) and (rE+1,jE) ----
    float sA = 0.f, sB = 0.f;
    const float* rr_ = &red[jgE*36 + cE];
    #pragma unroll
    for (int k2 = 0; k2 < 16; k2++) {
      sA += rr_[k2*580];
      sB += rr_[k2*580 + 1];
    }
    float holdA = h_s[rE*576 + hIdxE];
    float holdB = h_s[(rE+1)*576 + hIdxE];
    float hcA = fmaxf(sA + bhE + preA, 0.f);
    float hcB = fmaxf(sB + bhE + preB, 0.f);
    float hnA = (1.f - aE)*holdA + aE*hcA;
    float hnB = (1.f - aE)*holdB + aE*hcB;
    if (jvE) {
      store_xcd(&hnxt[(size_t)(r0 + rE)*NHID + jE],     hnA);   // exchange: bypass stores
      store_xcd(&hnxt[(size_t)(r0 + rE + 1)*NHID + jE], hnB);
      hid[offA] = hnA;                                           // stream: normal stores
      hid[offB] = hnB;
      if (t == TLEN-1) {
        hfinal[(size_t)(r0 + rE)*NHID + jE]     = hnA;
        hfinal[(size_t)(r0 + rE + 1)*NHID + jE] = hnB;
      }
    }
    __syncthreads();   // emits s_waitcnt vmcnt(0) before s_barrier: exchange stores acked

    // group barrier: RELAXED add + spin (no wbl2 / no buffer_inv)
    if (tid == 0) {
      __hip_atomic_fetch_add(&cnt[t], 1, __ATOMIC_RELAXED, __HIP_MEMORY_SCOPE_AGENT);
      int guard = 0;
      while (__hip_atomic_load(&cnt[t], __ATOMIC_RELAXED, __HIP_MEMORY_SCOPE_AGENT) < 8) {
        if (++guard > (1 << 21)) break;   // bail-out: wrong answer, never a hang
        __builtin_amdgcn_s_sleep(1);
      }
    }
    __syncthreads();
  }
}

// ---------------- output projection: out = hidden_list @ W_outT + b_out ----------------
__global__ __launch_bounds__(256) void out_proj_kernel(
    const float* __restrict__ hid, const float* __restrict__ ws,
    const float* __restrict__ b_out, float* __restrict__ outp)
{
  __shared__ float A_s[100][68];
  __shared__ float W_s[100][68];
  const int r0 = blockIdx.x * 64;
  const int o0 = blockIdx.y * 64;
  const int tid = threadIdx.x;
  const int jj = tid & 15, rr = tid >> 4;
  float acc[4][4] = {};

  for (int kc = 0; kc < NHID; kc += 100) {
    __syncthreads();
    for (int idx = tid; idx < 64*25; idx += 256) {
      int r = idx / 25, kq = idx % 25;
      float4 v = ((const float4*)(hid + (size_t)(r0 + r)*NHID + kc))[kq];
      A_s[4*kq+0][r] = v.x; A_s[4*kq+1][r] = v.y; A_s[4*kq+2][r] = v.z; A_s[4*kq+3][r] = v.w;
    }
    for (int idx = tid; idx < 100*16; idx += 256) {
      int k = idx / 16, c4 = idx % 16;
      int o = o0 + c4*4;
      float4 v = make_float4(0.f,0.f,0.f,0.f);
      if (o + 3 < NOUT) v = *(const float4*)(ws + WS_WOT + (size_t)(kc + k)*NOUT + o);
      *(float4*)&W_s[k][c4*4] = v;
    }
    __syncthreads();
    #pragma unroll 2
    for (int k = 0; k < 100; k++) {
      float4 av = *(const float4*)&A_s[k][rr*4];
      float4 wv = *(const float4*)&W_s[k][jj*4];
      float aa[4] = {av.x, av.y, av.z, av.w};
      float ww[4] = {wv.x, wv.y, wv.z, wv.w};
      #pragma unroll
      for (int r = 0; r < 4; r++)
        #pragma unroll
        for (int c = 0; c < 4; c++)
          acc[r][c] = fmaf(aa[r], ww[c], acc[r][c]);
    }
  }
  #pragma unroll
  for (int r = 0; r < 4; r++) {
    int row = r0 + rr*4 + r;
    #pragma unroll
    for (int c = 0; c < 4; c++) {
      int o = o0 + jj*4 + c;
      if (o < NOUT) outp[(size_t)row*NOUT + o] = acc[r][c] + b_out[o];
    }
  }
}

extern "C" void kernel_launch(void* const* d_in, const int* in_sizes, int n_in,
                              void* d_out, int out_size, void* d_ws, size_t ws_size,
                              hipStream_t stream)
{
  const float* input   = (const float*)d_in[0];
  const float* hidden0 = (const float*)d_in[1];
  const float* W_in    = (const float*)d_in[2];
  const float* b_in    = (const float*)d_in[3];
  const float* W_ih    = (const float*)d_in[4];
  const float* b_ih    = (const float*)d_in[5];
  const float* W_hh    = (const float*)d_in[6];
  const float* b_hh    = (const float*)d_in[7];
  const float* W_out   = (const float*)d_in[8];
  const float* b_out   = (const float*)d_in[9];
  const float* alpha_w = (const float*)d_in[10];

  float* ws   = (float*)d_ws;
  float* hid  = (float*)d_out;                        // [256][300][500]
  float* outp = hid  + (size_t)BATCH*TLEN*NHID;       // [256][300][100]
  float* hfin = outp + (size_t)BATCH*TLEN*NOUT;       // [256][500]

  hipLaunchKernelGGL(prep_kernel,     dim3(931),      dim3(256), 0, stream,
                     W_in, b_in, W_ih, b_ih, W_out, hidden0, ws);
  hipLaunchKernelGGL(pre_gemm_kernel, dim3(1200, 8),  dim3(256), 0, stream,
                     input, ws, hid);
  hipLaunchKernelGGL(rnn_step_kernel, dim3(256),      dim3(256), 0, stream,
                     W_hh, b_hh, alpha_w, ws, hid, hfin);
  hipLaunchKernelGGL(out_proj_kernel, dim3(1200, 2),  dim3(256), 0, stream,
                     hid, ws, b_out, outp);
}